// Round 14
// baseline (194.574 us; speedup 1.0000x reference)
//
#include <hip/hip_runtime.h>
#include <hip/hip_fp16.h>

#define BB 16
#define NN 1024
#define ND 32
#define GC1 64
#define GC2 32
#define AUXD 128
#define ZD 16
#define TN 64

#define FMA4(A, sc, V) {A.x += (sc)*(V).x; A.y += (sc)*(V).y; A.z += (sc)*(V).z; A.w += (sc)*(V).w;}

// pack two floats -> half2 bits in a float (no address-of: bit_cast only)
__device__ __forceinline__ float pk2h(float a, float b) {
  __half2 h = __floats2half2_rn(a, b);
  return __builtin_bit_cast(float, h);
}
// unpack half2 bits (carried in a float) -> float2
__device__ __forceinline__ float2 uph2(float f) {
  __half2 h = __builtin_bit_cast(__half2, f);
  return __half22float2(h);
}

// ---------------- K0: pure stream fold adj_raw -> adj_s(fp16), COALESCED via LDS.
// 8192 blocks x 256 threads; block handles 2048 entries (40 KB raw).
// Load: lane-linear float4 (4 KB/instr, perfectly coalesced).
// Fold: LDS reads at word-stride 10 -> 2-way bank alias (free); half2 stores contiguous.
__global__ __launch_bounds__(256) void k0(const float* __restrict__ adj_raw,
                                          __half* __restrict__ adj_sh) {
  __shared__ float raw[10240];            // 40 KB
  int t = threadIdx.x;
  size_t E0 = (size_t)blockIdx.x * 2048;
  const float4* gp = (const float4*)(adj_raw + E0 * 5);
  float4* r4 = (float4*)raw;
#pragma unroll
  for (int q = 0; q < 10; ++q) r4[q * 256 + t] = gp[q * 256 + t];
  __syncthreads();
#pragma unroll
  for (int s = 0; s < 4; ++s) {
    int base = 10 * t + 2560 * s;         // entries 2t+512s, 2t+1+512s
    float a0 = raw[base + 1] + raw[base + 2] + raw[base + 3] + raw[base + 4];
    float a1 = raw[base + 6] + raw[base + 7] + raw[base + 8] + raw[base + 9];
    float pk = pk2h(a0, a1);
    *(float*)(void*)(adj_sh + E0 + 2 * t + 512 * s) = pk;
  }
}

// ---------------- K1: h1lin = node @ W1 + b1
__global__ __launch_bounds__(256) void k1(const float* __restrict__ node,
                                          const float* __restrict__ W1,
                                          const float* __restrict__ b1,
                                          float* __restrict__ h1lin) {
  __shared__ float W1s[ND][GC1];
  __shared__ float b1s[GC1];
  __shared__ float nds[4][ND];
  int t = threadIdx.x;
  for (int i = t; i < ND * GC1; i += 256) W1s[i / GC1][i % GC1] = W1[i];
  if (t < GC1) b1s[t] = b1[t];
  int row0 = blockIdx.x * 4;
  if (t < 4 * ND) nds[t / ND][t % ND] = node[(size_t)row0 * ND + t];
  __syncthreads();
  int r = t >> 6, d = t & 63;
  float acc = b1s[d];
#pragma unroll
  for (int k = 0; k < ND; ++k) acc += nds[r][k] * W1s[k][d];
  h1lin[(size_t)(row0 + r) * GC1 + d] = acc;
}

// ---------------- K2S: msgpart(fp16)[mq] = adj_s(fp16)_panel @ h1lin
// clone of k4 structure, 64-wide output. grid 1024 = b(16) x mq(4) x rt(16);
// per block 64 rows x 256 m, 4 tiles of 64 m.
#define TMK2S 64
#define NTK2S 4
__global__ __launch_bounds__(256, 4) void k2s(const __half* __restrict__ adj_sh,
                                              const float* __restrict__ h1lin,
                                              __half* __restrict__ msgh) {
  __shared__ float a_s[TMK2S][TN + 4];    // [m][row] 64x68 = 17.4 KB
  __shared__ float4 h1s4[TMK2S * 16];     // [m][colf4] 64x64 floats = 16 KB
  int t = threadIdx.x;
  int blk = blockIdx.x;
  int rt = blk & 15, mq = (blk >> 4) & 3, b = blk >> 6;
  int n0 = rt * TN;
  int mbase = mq * 256;
  const float4* a4h = (const float4*)adj_sh;   // 1 float4 = 8 halfs
  const float4* h1b4 = (const float4*)(h1lin + (size_t)b * NN * GC1);
  int rg = t >> 4, cg = t & 15;           // compute: rows 4rg.., cols 4cg..

  float4 areg[2];
  float4 hreg[4];
  float4 acc[4];
#pragma unroll
  for (int i = 0; i < 4; ++i) acc[i] = make_float4(0.f, 0.f, 0.f, 0.f);

  // prologue
  {
#pragma unroll
    for (int k = 0; k < 2; ++k) {
      int id = k * 256 + t;
      int row = id >> 3, c8 = id & 7;
      areg[k] = a4h[(((size_t)(b * NN + n0 + row)) * NN + mbase + c8 * 8) >> 3];
    }
#pragma unroll
    for (int k = 0; k < 4; ++k) hreg[k] = h1b4[mbase * 16 + k * 256 + t];
  }

  for (int tile = 0; tile < NTK2S; ++tile) {
    int m0 = mbase + tile * TMK2S;
    __syncthreads();
#pragma unroll
    for (int k = 0; k < 2; ++k) {
      int id = k * 256 + t;
      int row = id >> 3, c8 = id & 7;
      float2 v0 = uph2(areg[k].x);
      float2 v1 = uph2(areg[k].y);
      float2 v2 = uph2(areg[k].z);
      float2 v3 = uph2(areg[k].w);
      a_s[c8 * 8 + 0][row] = v0.x;
      a_s[c8 * 8 + 1][row] = v0.y;
      a_s[c8 * 8 + 2][row] = v1.x;
      a_s[c8 * 8 + 3][row] = v1.y;
      a_s[c8 * 8 + 4][row] = v2.x;
      a_s[c8 * 8 + 5][row] = v2.y;
      a_s[c8 * 8 + 6][row] = v3.x;
      a_s[c8 * 8 + 7][row] = v3.y;
    }
#pragma unroll
    for (int k = 0; k < 4; ++k) h1s4[k * 256 + t] = hreg[k];
    __syncthreads();
    if (tile + 1 < NTK2S) {
      int m1 = m0 + TMK2S;
#pragma unroll
      for (int k = 0; k < 2; ++k) {
        int id = k * 256 + t;
        int row = id >> 3, c8 = id & 7;
        areg[k] = a4h[(((size_t)(b * NN + n0 + row)) * NN + m1 + c8 * 8) >> 3];
      }
#pragma unroll
      for (int k = 0; k < 4; ++k) hreg[k] = h1b4[m1 * 16 + k * 256 + t];
    }
#pragma unroll
    for (int m = 0; m < TMK2S; ++m) {
      float4 av = *(const float4*)&a_s[m][rg * 4];
      float4 hv = h1s4[m * 16 + cg];
      FMA4(acc[0], av.x, hv);
      FMA4(acc[1], av.y, hv);
      FMA4(acc[2], av.z, hv);
      FMA4(acc[3], av.w, hv);
    }
  }
  size_t mpo = (size_t)mq * ((size_t)BB * NN * GC1);
#pragma unroll
  for (int i = 0; i < 4; ++i) {
    float2 pk = make_float2(pk2h(acc[i].x, acc[i].y), pk2h(acc[i].z, acc[i].w));
    *(float2*)(void*)(msgh + mpo + ((size_t)(b * NN) + n0 + rg * 4 + i) * GC1 + cg * 4) = pk;
  }
}

// ---------------- K2 (fallback, ws too small): fused stream+fold+einsum from raw
#define TMK2 32
#define NTK2 8
__global__ __launch_bounds__(256, 4) void k2(const float* __restrict__ adj_raw,
                                             const float* __restrict__ h1lin,
                                             __half* __restrict__ msgh) {
  __shared__ float a_s[TMK2][TN + 4];
  __shared__ float4 h1s4[TMK2 * 16];
  int t = threadIdx.x;
  int blk = blockIdx.x;
  int rt = blk & 15, mq = (blk >> 4) & 3, b = blk >> 6;
  int n0 = rt * TN;
  int mbase = mq * 256;
  const float4* h1b4 = (const float4*)(h1lin + (size_t)b * NN * GC1);
  int arow = t >> 2, aq = t & 3;
  const float* rawrow = adj_raw + (size_t)(b * NN + n0 + arow) * ((size_t)NN * 5);
  int rg = t >> 4, cg = t & 15;

  float4 pf[10];
  float* pfv = (float*)pf;
  float4 hreg[2];
  float4 acc[4];
#pragma unroll
  for (int i = 0; i < 4; ++i) acc[i] = make_float4(0.f, 0.f, 0.f, 0.f);

  {
    const float4* gp = (const float4*)(rawrow + (size_t)(mbase + aq * 8) * 5);
#pragma unroll
    for (int q = 0; q < 10; ++q) pf[q] = gp[q];
#pragma unroll
    for (int k = 0; k < 2; ++k) hreg[k] = h1b4[mbase * 16 + k * 256 + t];
  }

  for (int tile = 0; tile < NTK2; ++tile) {
    int m0 = mbase + tile * TMK2;
    __syncthreads();
    float s[8];
#pragma unroll
    for (int i = 0; i < 8; ++i) {
      s[i] = pfv[5 * i + 1] + pfv[5 * i + 2] + pfv[5 * i + 3] + pfv[5 * i + 4];
      a_s[aq * 8 + i][arow] = s[i];
    }
#pragma unroll
    for (int k = 0; k < 2; ++k) h1s4[k * 256 + t] = hreg[k];
    __syncthreads();
    if (tile + 1 < NTK2) {
      const float4* gp = (const float4*)(rawrow + (size_t)(m0 + TMK2 + aq * 8) * 5);
#pragma unroll
      for (int q = 0; q < 10; ++q) pf[q] = gp[q];
#pragma unroll
      for (int k = 0; k < 2; ++k) hreg[k] = h1b4[(m0 + TMK2) * 16 + k * 256 + t];
    }
#pragma unroll
    for (int m = 0; m < TMK2; ++m) {
      float4 av = *(const float4*)&a_s[m][rg * 4];
      float4 hv = h1s4[m * 16 + cg];
      FMA4(acc[0], av.x, hv);
      FMA4(acc[1], av.y, hv);
      FMA4(acc[2], av.z, hv);
      FMA4(acc[3], av.w, hv);
    }
  }
  size_t mpo = (size_t)mq * ((size_t)BB * NN * GC1);
#pragma unroll
  for (int i = 0; i < 4; ++i) {
    float2 pk = make_float2(pk2h(acc[i].x, acc[i].y), pk2h(acc[i].z, acc[i].w));
    *(float2*)(void*)(msgh + mpo + ((size_t)(b * NN) + n0 + rg * 4 + i) * GC1 + cg * 4) = pk;
  }
}

// ---------------- K3: h2lin = (sum_q msgpart(fp16)[q] + h1lin) @ W2 + b2
__global__ __launch_bounds__(256) void k3(const __half* __restrict__ msgh,
                                          const float* __restrict__ h1lin,
                                          const float* __restrict__ W2,
                                          const float* __restrict__ b2,
                                          float* __restrict__ h2lin) {
  __shared__ float W2s[GC1][GC2];
  __shared__ float b2s[GC2];
  __shared__ float xs[8][GC1];
  int t = threadIdx.x;
  for (int i = t; i < GC1 * GC2; i += 256) W2s[i / GC2][i % GC2] = W2[i];
  if (t < GC2) b2s[t] = b2[t];
  size_t base = (size_t)blockIdx.x * 8 * GC1;
  const size_t QSH = (size_t)BB * NN * GC1;
  {
    int rr = t >> 5, kk = t & 31;
    size_t fidx = base + (size_t)rr * GC1 + kk * 2;
    float2 v = *(const float2*)&h1lin[fidx];
#pragma unroll
    for (int q = 0; q < 4; ++q) {
      float2 mv = uph2(*(const float*)(const void*)(msgh + q * QSH + fidx));
      v.x += mv.x; v.y += mv.y;
    }
    xs[rr][kk * 2] = v.x;
    xs[rr][kk * 2 + 1] = v.y;
  }
  __syncthreads();
  int r = t >> 5, dd = t & 31;
  float acc = b2s[dd];
#pragma unroll
  for (int k = 0; k < GC1; ++k) acc += xs[r][k] * W2s[k][dd];
  h2lin[(size_t)(blockIdx.x * 8 + r) * GC2 + dd] = acc;
}

// ---------------- K4: hpart(fp32)[mq] = adj_s(fp16)_panel @ h2lin  (self added in k5)
#define TMK4 64
#define NTK4 4
__global__ __launch_bounds__(256, 4) void k4(const __half* __restrict__ adj_sh,
                                             const float* __restrict__ h2lin,
                                             float* __restrict__ hpart) {
  __shared__ float a_s[TMK4][TN + 4];
  __shared__ float4 h2s4[TMK4 * 8];
  int t = threadIdx.x;
  int blk = blockIdx.x;
  int rt = blk & 15, mq = (blk >> 4) & 3, b = blk >> 6;
  int n0 = rt * TN;
  int mbase = mq * 256;
  const float4* a4h = (const float4*)adj_sh;
  const float4* h2b4 = (const float4*)(h2lin + (size_t)b * NN * GC2);
  int rg = t >> 4, cg = t & 15;

  float4 areg[2];
  float4 hreg[2];
  float2 acc[4];
#pragma unroll
  for (int i = 0; i < 4; ++i) acc[i] = make_float2(0.f, 0.f);

  {
#pragma unroll
    for (int k = 0; k < 2; ++k) {
      int id = k * 256 + t;
      int row = id >> 3, c8 = id & 7;
      areg[k] = a4h[(((size_t)(b * NN + n0 + row)) * NN + mbase + c8 * 8) >> 3];
    }
#pragma unroll
    for (int k = 0; k < 2; ++k) hreg[k] = h2b4[mbase * 8 + k * 256 + t];
  }

  for (int tile = 0; tile < NTK4; ++tile) {
    int m0 = mbase + tile * TMK4;
    __syncthreads();
#pragma unroll
    for (int k = 0; k < 2; ++k) {
      int id = k * 256 + t;
      int row = id >> 3, c8 = id & 7;
      float2 v0 = uph2(areg[k].x);
      float2 v1 = uph2(areg[k].y);
      float2 v2 = uph2(areg[k].z);
      float2 v3 = uph2(areg[k].w);
      a_s[c8 * 8 + 0][row] = v0.x;
      a_s[c8 * 8 + 1][row] = v0.y;
      a_s[c8 * 8 + 2][row] = v1.x;
      a_s[c8 * 8 + 3][row] = v1.y;
      a_s[c8 * 8 + 4][row] = v2.x;
      a_s[c8 * 8 + 5][row] = v2.y;
      a_s[c8 * 8 + 6][row] = v3.x;
      a_s[c8 * 8 + 7][row] = v3.y;
    }
#pragma unroll
    for (int k = 0; k < 2; ++k) h2s4[k * 256 + t] = hreg[k];
    __syncthreads();
    if (tile + 1 < NTK4) {
      int m1 = m0 + TMK4;
#pragma unroll
      for (int k = 0; k < 2; ++k) {
        int id = k * 256 + t;
        int row = id >> 3, c8 = id & 7;
        areg[k] = a4h[(((size_t)(b * NN + n0 + row)) * NN + m1 + c8 * 8) >> 3];
      }
#pragma unroll
      for (int k = 0; k < 2; ++k) hreg[k] = h2b4[m1 * 8 + k * 256 + t];
    }
#pragma unroll
    for (int m = 0; m < TMK4; ++m) {
      float4 av = *(const float4*)&a_s[m][rg * 4];
      float2 hv = ((const float2*)h2s4)[m * 16 + cg];
      acc[0].x += av.x * hv.x; acc[0].y += av.x * hv.y;
      acc[1].x += av.y * hv.x; acc[1].y += av.y * hv.y;
      acc[2].x += av.z * hv.x; acc[2].y += av.z * hv.y;
      acc[3].x += av.w * hv.x; acc[3].y += av.w * hv.y;
    }
  }
  size_t hpo = (size_t)mq * ((size_t)BB * NN * GC2);
#pragma unroll
  for (int i = 0; i < 4; ++i) {
    *(float2*)(hpart + hpo + ((size_t)(b * NN) + n0 + rg * 4 + i) * GC2 + cg * 2) = acc[i];
  }
}

// ---------------- K5: gated sum over nodes; x = h2lin + sum_q hpart(fp32)[q], node
#define TR 32
__global__ __launch_bounds__(256) void k5(const float* __restrict__ hpart,
                                          const float* __restrict__ h2lin,
                                          const float* __restrict__ node,
                                          const float* __restrict__ Ws,
                                          const float* __restrict__ bs,
                                          const float* __restrict__ Wt,
                                          const float* __restrict__ bt,
                                          float* __restrict__ partials) {
  __shared__ float xs[TR][GC2 + ND];
  __shared__ float red[2][AUXD];
  int t = threadIdx.x;
  int blk = blockIdx.x;
  int b = blk >> 5;
  int n0 = (blk & 31) * TR;
  const size_t QS2 = (size_t)BB * NN * GC2;
  for (int i = t; i < TR * GC2; i += 256) {
    int rr = i >> 5, kk = i & 31;
    size_t idx = ((size_t)(b * NN + n0 + rr)) * GC2 + kk;
    float v = h2lin[idx];
#pragma unroll
    for (int q = 0; q < 4; ++q) v += hpart[q * QS2 + idx];
    xs[rr][kk] = v;
  }
  for (int i = t; i < TR * ND; i += 256) {
    int rr = i >> 5, kk = i & 31;
    xs[rr][GC2 + kk] = node[((size_t)(b * NN + n0 + rr)) * ND + kk];
  }
  int c = t & 127;
  int g = t >> 7;
  float wsc[64], wtc[64];
#pragma unroll
  for (int k = 0; k < 64; ++k) {
    wsc[k] = Ws[(size_t)k * AUXD + c];
    wtc[k] = Wt[(size_t)k * AUXD + c];
  }
  float bsv = bs[c], btv = bt[c];
  __syncthreads();
  float part = 0.f;
  for (int rr = g * (TR / 2); rr < (g + 1) * (TR / 2); ++rr) {
    float as_ = bsv, at_ = btv;
#pragma unroll
    for (int k = 0; k < 64; ++k) {
      float xv = xs[rr][k];
      as_ += xv * wsc[k];
      at_ += xv * wtc[k];
    }
    float sg = 1.f / (1.f + __expf(-as_));
    float e2 = __expf(2.f * at_);
    float th = 1.f - 2.f / (e2 + 1.f);
    part += sg * th;
  }
  red[g][c] = part;
  __syncthreads();
  if (t < AUXD) partials[(size_t)blk * AUXD + t] = red[0][t] + red[1][t];
}

// ---------------- K4_raw fallback (ws too small): h = adj(raw) @ h2 + h2 -> hbuf(fp32)
#define TN2 16
#define TM2 128
__global__ __launch_bounds__(256) void k4_raw(const float* __restrict__ adj_src,
                                              const float* __restrict__ h2lin,
                                              float* __restrict__ hout) {
  __shared__ float a_s[TN2][TM2 + 4];
  __shared__ float h2s[TM2][GC2];
  int t = threadIdx.x;
  int blk = blockIdx.x;
  int b = blk >> 6;
  int n0 = (blk & 63) * TN2;
  const float4* h2b4 = (const float4*)(h2lin + (size_t)b * NN * GC2);
  int r = t >> 4;
  int cg = (t >> 1) & 7;
  int hh = t & 1;
  const size_t rs5 = (size_t)NN * 5;
  float4 acc = make_float4(0.f, 0.f, 0.f, 0.f);

  for (int tile = 0; tile < NN / TM2; ++tile) {
    int m0 = tile * TM2;
    float4 pfr[2][5];
    int x = t & 31, rowp = t >> 5;
#pragma unroll
    for (int p = 0; p < 2; ++p) {
      const float* rp = adj_src + (size_t)(b * NN + n0 + rowp + 8 * p) * rs5 + (size_t)(m0 + 4 * x) * 5;
#pragma unroll
      for (int q = 0; q < 5; ++q) pfr[p][q] = *(const float4*)(rp + 4 * q);
    }
    float4 hf[4];
#pragma unroll
    for (int q = 0; q < 4; ++q) hf[q] = h2b4[m0 * (GC2 / 4) + q * 256 + t];
    __syncthreads();
#pragma unroll
    for (int p = 0; p < 2; ++p) {
      int row = rowp + 8 * p;
      float4 s;
      s.x = pfr[p][0].y + pfr[p][0].z + pfr[p][0].w + pfr[p][1].x;
      s.y = pfr[p][1].z + pfr[p][1].w + pfr[p][2].x + pfr[p][2].y;
      s.z = pfr[p][2].w + pfr[p][3].x + pfr[p][3].y + pfr[p][3].z;
      s.w = pfr[p][4].x + pfr[p][4].y + pfr[p][4].z + pfr[p][4].w;
      *(float4*)&a_s[row][4 * x] = s;
    }
#pragma unroll
    for (int q = 0; q < 4; ++q) ((float4*)h2s)[q * 256 + t] = hf[q];
    __syncthreads();
#pragma unroll 4
    for (int mm = 0; mm < TM2 / 2; mm += 4) {
      int m = hh * (TM2 / 2) + mm;
      float4 av = *(const float4*)&a_s[r][m];
      const float* hp = &h2s[m][cg * 4];
      float4 h0 = *(const float4*)(hp);
      float4 h1v = *(const float4*)(hp + GC2);
      float4 h2v = *(const float4*)(hp + 2 * GC2);
      float4 h3v = *(const float4*)(hp + 3 * GC2);
      acc.x += av.x * h0.x + av.y * h1v.x + av.z * h2v.x + av.w * h3v.x;
      acc.y += av.x * h0.y + av.y * h1v.y + av.z * h2v.y + av.w * h3v.y;
      acc.z += av.x * h0.z + av.y * h1v.z + av.z * h2v.z + av.w * h3v.z;
      acc.w += av.x * h0.w + av.y * h1v.w + av.z * h2v.w + av.w * h3v.w;
    }
    __syncthreads();
  }
  float4* red = (float4*)a_s;
  red[(hh * TN2 + r) * 8 + cg] = acc;
  __syncthreads();
  if (t < 128) {
    int rr = t >> 3, cc = t & 7;
    float4 s0 = red[(0 * TN2 + rr) * 8 + cc];
    float4 s1 = red[(1 * TN2 + rr) * 8 + cc];
    size_t row = (size_t)(b * NN + n0 + rr);
    float4 sv = *(const float4*)(h2lin + row * GC2 + cc * 4);
    float4 o;
    o.x = s0.x + s1.x + sv.x;
    o.y = s0.y + s1.y + sv.y;
    o.z = s0.z + s1.z + sv.z;
    o.w = s0.w + s1.w + sv.w;
    *(float4*)(hout + row * GC2 + cc * 4) = o;
  }
}

// ---------------- K5_fb (fallback path only): gated sum over nodes from fp32 hbuf
__global__ __launch_bounds__(256) void k5_fb(const float* __restrict__ hbuf,
                                             const float* __restrict__ node,
                                             const float* __restrict__ Ws,
                                             const float* __restrict__ bs,
                                             const float* __restrict__ Wt,
                                             const float* __restrict__ bt,
                                             float* __restrict__ partials) {
  __shared__ float xs[TR][GC2 + ND];
  __shared__ float red[2][AUXD];
  int t = threadIdx.x;
  int blk = blockIdx.x;
  int b = blk >> 5;
  int n0 = (blk & 31) * TR;
  for (int i = t; i < TR * GC2; i += 256) {
    int rr = i >> 5, kk = i & 31;
    xs[rr][kk] = hbuf[((size_t)(b * NN + n0 + rr)) * GC2 + kk];
  }
  for (int i = t; i < TR * ND; i += 256) {
    int rr = i >> 5, kk = i & 31;
    xs[rr][GC2 + kk] = node[((size_t)(b * NN + n0 + rr)) * ND + kk];
  }
  int c = t & 127;
  int g = t >> 7;
  float wsc[64], wtc[64];
#pragma unroll
  for (int k = 0; k < 64; ++k) {
    wsc[k] = Ws[(size_t)k * AUXD + c];
    wtc[k] = Wt[(size_t)k * AUXD + c];
  }
  float bsv = bs[c], btv = bt[c];
  __syncthreads();
  float part = 0.f;
  for (int rr = g * (TR / 2); rr < (g + 1) * (TR / 2); ++rr) {
    float as_ = bsv, at_ = btv;
#pragma unroll
    for (int k = 0; k < 64; ++k) {
      float xv = xs[rr][k];
      as_ += xv * wsc[k];
      at_ += xv * wtc[k];
    }
    float sg = 1.f / (1.f + __expf(-as_));
    float e2 = __expf(2.f * at_);
    float th = 1.f - 2.f / (e2 + 1.f);
    part += sg * th;
  }
  red[g][c] = part;
  __syncthreads();
  if (t < AUXD) partials[(size_t)blk * AUXD + t] = red[0][t] + red[1][t];
}

// ---------------- K6: reduce partials, tanh, MLP -> head
__global__ __launch_bounds__(128) void k6(const float* __restrict__ partials,
                                          const float* __restrict__ Wm1, const float* __restrict__ bm1,
                                          const float* __restrict__ Wm2, const float* __restrict__ bm2,
                                          const float* __restrict__ Wl, const float* __restrict__ bl,
                                          float* __restrict__ out) {
  __shared__ float g_s[AUXD];
  __shared__ float g2_s[AUXD];
  int t = threadIdx.x;
  int b = blockIdx.x;
  float s = 0.f;
  for (int j = 0; j < 32; ++j) s += partials[((size_t)(b * 32 + j)) * AUXD + t];
  float e2 = __expf(2.f * s);
  g_s[t] = 1.f - 2.f / (e2 + 1.f);
  __syncthreads();
  float acc = bm1[t];
#pragma unroll 16
  for (int k = 0; k < AUXD; ++k) acc += g_s[k] * Wm1[(size_t)k * 128 + t];
  e2 = __expf(2.f * acc);
  g2_s[t] = 1.f - 2.f / (e2 + 1.f);
  __syncthreads();
  acc = bm2[t];
#pragma unroll 16
  for (int k = 0; k < 128; ++k) acc += g2_s[k] * Wm2[(size_t)k * 128 + t];
  e2 = __expf(2.f * acc);
  float g3 = 1.f - 2.f / (e2 + 1.f);
  __syncthreads();
  g_s[t] = g3;
  __syncthreads();
  if (t < ZD) {
    float a = bl[t];
#pragma unroll 16
    for (int k = 0; k < 128; ++k) a += g_s[k] * Wl[(size_t)k * ZD + t];
    out[(size_t)b * ZD + t] = a;
  }
}

extern "C" void kernel_launch(void* const* d_in, const int* in_sizes, int n_in,
                              void* d_out, int out_size, void* d_ws, size_t ws_size,
                              hipStream_t stream) {
  const float* node = (const float*)d_in[0];
  const float* adj_raw = (const float*)d_in[1];
  const float* W1 = (const float*)d_in[2];
  const float* b1 = (const float*)d_in[3];
  const float* W2 = (const float*)d_in[4];
  const float* b2 = (const float*)d_in[5];
  const float* Ws = (const float*)d_in[6];
  const float* bs = (const float*)d_in[7];
  const float* Wt = (const float*)d_in[8];
  const float* bt = (const float*)d_in[9];
  const float* Wm1 = (const float*)d_in[10];
  const float* bm1 = (const float*)d_in[11];
  const float* Wm2 = (const float*)d_in[12];
  const float* bm2 = (const float*)d_in[13];
  const float* Wl = (const float*)d_in[14];
  const float* bl = (const float*)d_in[15];
  float* out = (float*)d_out;
  float* ws = (float*)d_ws;

  size_t o_h1 = 0;                                       // floats
  size_t o_msgp = o_h1 + (size_t)BB * NN * GC1;          // msg fp16: 4 slices = 2M floats
  size_t o_h2 = o_msgp + 2 * (size_t)BB * NN * GC1;
  size_t o_hp = o_h2 + (size_t)BB * NN * GC2;            // hpart fp32: 4 slices (fallback hbuf = slice 0)
  size_t o_part = o_hp + 4 * (size_t)BB * NN * GC2;
  size_t o_adj = o_part + (size_t)512 * AUXD;            // adj_s fp16
  size_t need_bytes = o_adj * sizeof(float) + (size_t)BB * NN * NN * sizeof(__half);
  bool store = (ws_size >= need_bytes);

  float* h1lin = ws + o_h1;
  __half* msgh = (__half*)(ws + o_msgp);
  float* h2lin = ws + o_h2;
  float* hpart = ws + o_hp;
  float* part = ws + o_part;
  __half* adj_sh = (__half*)(ws + o_adj);

  k1<<<4096, 256, 0, stream>>>(node, W1, b1, h1lin);
  if (store) {
    k0<<<8192, 256, 0, stream>>>(adj_raw, adj_sh);
    k2s<<<1024, 256, 0, stream>>>(adj_sh, h1lin, msgh);
    k3<<<2048, 256, 0, stream>>>(msgh, h1lin, W2, b2, h2lin);
    k4<<<1024, 256, 0, stream>>>(adj_sh, h2lin, hpart);
    k5<<<512, 256, 0, stream>>>(hpart, h2lin, node, Ws, bs, Wt, bt, part);
  } else {
    k2<<<1024, 256, 0, stream>>>(adj_raw, h1lin, msgh);
    k3<<<2048, 256, 0, stream>>>(msgh, h1lin, W2, b2, h2lin);
    k4_raw<<<1024, 256, 0, stream>>>(adj_raw, h2lin, hpart);
    k5_fb<<<512, 256, 0, stream>>>(hpart, node, Ws, bs, Wt, bt, part);
  }
  k6<<<16, 128, 0, stream>>>(part, Wm1, bm1, Wm2, bm2, Wl, bl, out);
}

// Round 15
// 179.732 us; speedup vs baseline: 1.0826x; 1.0826x over previous
//
#include <hip/hip_runtime.h>
#include <hip/hip_fp16.h>

#define BB 16
#define NN 1024
#define ND 32
#define GC1 64
#define GC2 32
#define AUXD 128
#define ZD 16
#define TN 64

#define FMA4(A, sc, V) {A.x += (sc)*(V).x; A.y += (sc)*(V).y; A.z += (sc)*(V).z; A.w += (sc)*(V).w;}

// pack two floats -> half2 bits in a float (no address-of: bit_cast only)
__device__ __forceinline__ float pk2h(float a, float b) {
  __half2 h = __floats2half2_rn(a, b);
  return __builtin_bit_cast(float, h);
}
// unpack half2 bits (carried in a float) -> float2
__device__ __forceinline__ float2 uph2(float f) {
  __half2 h = __builtin_bit_cast(__half2, f);
  return __half22float2(h);
}

// ---------------- K1: h1lin = node @ W1 + b1
__global__ __launch_bounds__(256) void k1(const float* __restrict__ node,
                                          const float* __restrict__ W1,
                                          const float* __restrict__ b1,
                                          float* __restrict__ h1lin) {
  __shared__ float W1s[ND][GC1];
  __shared__ float b1s[GC1];
  __shared__ float nds[4][ND];
  int t = threadIdx.x;
  for (int i = t; i < ND * GC1; i += 256) W1s[i / GC1][i % GC1] = W1[i];
  if (t < GC1) b1s[t] = b1[t];
  int row0 = blockIdx.x * 4;
  if (t < 4 * ND) nds[t / ND][t % ND] = node[(size_t)row0 * ND + t];
  __syncthreads();
  int r = t >> 6, d = t & 63;
  float acc = b1s[d];
#pragma unroll
  for (int k = 0; k < ND; ++k) acc += nds[r][k] * W1s[k][d];
  h1lin[(size_t)(row0 + r) * GC1 + d] = acc;
}

// ---------------- K2: stream adj_raw; write adj_s (fp16); msgpart(fp16)[mq] = a_panel @ h1lin
// r4 structure exactly: grid 1024 = b(16) x mq(4) x rowtile(16); 64 rows x 256 m, 8 tiles of 32 m
#define TMK2 32
#define NTK2 8
__global__ __launch_bounds__(256, 4) void k2(const float* __restrict__ adj_raw,
                                             const float* __restrict__ h1lin,
                                             __half* __restrict__ adj_sh,
                                             __half* __restrict__ msgh,
                                             int store_adj) {
  __shared__ float a_s[TMK2][TN + 4];     // [m][row] transposed
  __shared__ float4 h1s4[TMK2 * 16];      // [m][colf4] 32x64 floats
  int t = threadIdx.x;
  int blk = blockIdx.x;
  int rt = blk & 15, mq = (blk >> 4) & 3, b = blk >> 6;
  int n0 = rt * TN;
  int mbase = mq * 256;
  const float4* h1b4 = (const float4*)(h1lin + (size_t)b * NN * GC1);
  int arow = t >> 2, aq = t & 3;          // staging: row 0..63, m-octet 0..3
  const float* rawrow = adj_raw + (size_t)(b * NN + n0 + arow) * ((size_t)NN * 5);
  int rg = t >> 4, cg = t & 15;           // compute: rows 4rg.., cols 4cg..

  float4 pf[10];
  float* pfv = (float*)pf;
  float4 hreg[2];
  float4 acc[4];
#pragma unroll
  for (int i = 0; i < 4; ++i) acc[i] = make_float4(0.f, 0.f, 0.f, 0.f);

  // prologue: issue tile 0 loads
  {
    const float4* gp = (const float4*)(rawrow + (size_t)(mbase + aq * 8) * 5);
#pragma unroll
    for (int q = 0; q < 10; ++q) pf[q] = gp[q];
#pragma unroll
    for (int k = 0; k < 2; ++k) hreg[k] = h1b4[mbase * 16 + k * 256 + t];
  }

  for (int tile = 0; tile < NTK2; ++tile) {
    int m0 = mbase + tile * TMK2;
    __syncthreads();                      // prev compute done with LDS
    float s[8];
#pragma unroll
    for (int i = 0; i < 8; ++i) {
      s[i] = pfv[5 * i + 1] + pfv[5 * i + 2] + pfv[5 * i + 3] + pfv[5 * i + 4];
      a_s[aq * 8 + i][arow] = s[i];
    }
#pragma unroll
    for (int k = 0; k < 2; ++k) h1s4[k * 256 + t] = hreg[k];
    __syncthreads();
    // issue next-tile loads + adj_s store: overlap with compute below
    if (tile + 1 < NTK2) {
      const float4* gp = (const float4*)(rawrow + (size_t)(m0 + TMK2 + aq * 8) * 5);
#pragma unroll
      for (int q = 0; q < 10; ++q) pf[q] = gp[q];
#pragma unroll
      for (int k = 0; k < 2; ++k) hreg[k] = h1b4[(m0 + TMK2) * 16 + k * 256 + t];
    }
    if (store_adj) {
      float4* dst = (float4*)(adj_sh + (size_t)(b * NN + n0 + arow) * NN + m0 + aq * 8);
      *dst = make_float4(pk2h(s[0], s[1]), pk2h(s[2], s[3]),
                         pk2h(s[4], s[5]), pk2h(s[6], s[7]));
    }
#pragma unroll
    for (int m = 0; m < TMK2; ++m) {
      float4 av = *(const float4*)&a_s[m][rg * 4];
      float4 hv = h1s4[m * 16 + cg];
      FMA4(acc[0], av.x, hv);
      FMA4(acc[1], av.y, hv);
      FMA4(acc[2], av.z, hv);
      FMA4(acc[3], av.w, hv);
    }
  }
  size_t mpo = (size_t)mq * ((size_t)BB * NN * GC1);
#pragma unroll
  for (int i = 0; i < 4; ++i) {
    float2 pk = make_float2(pk2h(acc[i].x, acc[i].y), pk2h(acc[i].z, acc[i].w));
    *(float2*)(void*)(msgh + mpo + ((size_t)(b * NN) + n0 + rg * 4 + i) * GC1 + cg * 4) = pk;
  }
}

// ---------------- K3: h2lin = (sum_q msgpart(fp16)[q] + h1lin) @ W2 + b2
__global__ __launch_bounds__(256) void k3(const __half* __restrict__ msgh,
                                          const float* __restrict__ h1lin,
                                          const float* __restrict__ W2,
                                          const float* __restrict__ b2,
                                          float* __restrict__ h2lin) {
  __shared__ float W2s[GC1][GC2];
  __shared__ float b2s[GC2];
  __shared__ float xs[8][GC1];
  int t = threadIdx.x;
  for (int i = t; i < GC1 * GC2; i += 256) W2s[i / GC2][i % GC2] = W2[i];
  if (t < GC2) b2s[t] = b2[t];
  size_t base = (size_t)blockIdx.x * 8 * GC1;
  const size_t QSH = (size_t)BB * NN * GC1;
  {
    // 8 rows x 64 cols = 256 float2-units, one per thread
    int rr = t >> 5, kk = t & 31;
    size_t fidx = base + (size_t)rr * GC1 + kk * 2;
    float2 v = *(const float2*)&h1lin[fidx];
#pragma unroll
    for (int q = 0; q < 4; ++q) {
      float2 mv = uph2(*(const float*)(const void*)(msgh + q * QSH + fidx));
      v.x += mv.x; v.y += mv.y;
    }
    xs[rr][kk * 2] = v.x;
    xs[rr][kk * 2 + 1] = v.y;
  }
  __syncthreads();
  int r = t >> 5, dd = t & 31;
  float acc = b2s[dd];
#pragma unroll
  for (int k = 0; k < GC1; ++k) acc += xs[r][k] * W2s[k][dd];
  h2lin[(size_t)(blockIdx.x * 8 + r) * GC2 + dd] = acc;
}

// ---------------- K4: hpart(fp32)[mq] = adj_s(fp16)_panel @ h2lin  (self added in k5)
// grid 1024 = b(16) x mq(4) x rowtile(16); per block 64 rows x 256 m, 4 tiles of 64 m
#define TMK4 64
#define NTK4 4
__global__ __launch_bounds__(256, 4) void k4(const __half* __restrict__ adj_sh,
                                             const float* __restrict__ h2lin,
                                             float* __restrict__ hpart) {
  __shared__ float a_s[TMK4][TN + 4];     // [m][row]
  __shared__ float4 h2s4[TMK4 * 8];       // [m][colf4] 64x32 floats
  int t = threadIdx.x;
  int blk = blockIdx.x;
  int rt = blk & 15, mq = (blk >> 4) & 3, b = blk >> 6;
  int n0 = rt * TN;
  int mbase = mq * 256;
  const float4* a4h = (const float4*)adj_sh;   // 1 float4 = 8 halfs
  const float4* h2b4 = (const float4*)(h2lin + (size_t)b * NN * GC2);
  int rg = t >> 4, cg = t & 15;           // compute: rows 4rg.., cols 2cg..

  float4 areg[2];                         // 2 x 8 halfs = 64 rows x 64 m per tile
  float4 hreg[2];
  float2 acc[4];
#pragma unroll
  for (int i = 0; i < 4; ++i) acc[i] = make_float2(0.f, 0.f);

  // prologue
  {
#pragma unroll
    for (int k = 0; k < 2; ++k) {
      int id = k * 256 + t;
      int row = id >> 3, c8 = id & 7;
      areg[k] = a4h[(((size_t)(b * NN + n0 + row)) * NN + mbase + c8 * 8) >> 3];
    }
#pragma unroll
    for (int k = 0; k < 2; ++k) hreg[k] = h2b4[mbase * 8 + k * 256 + t];
  }

  for (int tile = 0; tile < NTK4; ++tile) {
    int m0 = mbase + tile * TMK4;
    __syncthreads();
#pragma unroll
    for (int k = 0; k < 2; ++k) {
      int id = k * 256 + t;
      int row = id >> 3, c8 = id & 7;
      float2 v0 = uph2(areg[k].x);
      float2 v1 = uph2(areg[k].y);
      float2 v2 = uph2(areg[k].z);
      float2 v3 = uph2(areg[k].w);
      a_s[c8 * 8 + 0][row] = v0.x;
      a_s[c8 * 8 + 1][row] = v0.y;
      a_s[c8 * 8 + 2][row] = v1.x;
      a_s[c8 * 8 + 3][row] = v1.y;
      a_s[c8 * 8 + 4][row] = v2.x;
      a_s[c8 * 8 + 5][row] = v2.y;
      a_s[c8 * 8 + 6][row] = v3.x;
      a_s[c8 * 8 + 7][row] = v3.y;
    }
#pragma unroll
    for (int k = 0; k < 2; ++k) h2s4[k * 256 + t] = hreg[k];
    __syncthreads();
    if (tile + 1 < NTK4) {
      int m1 = m0 + TMK4;
#pragma unroll
      for (int k = 0; k < 2; ++k) {
        int id = k * 256 + t;
        int row = id >> 3, c8 = id & 7;
        areg[k] = a4h[(((size_t)(b * NN + n0 + row)) * NN + m1 + c8 * 8) >> 3];
      }
#pragma unroll
      for (int k = 0; k < 2; ++k) hreg[k] = h2b4[m1 * 8 + k * 256 + t];
    }
#pragma unroll
    for (int m = 0; m < TMK4; ++m) {
      float4 av = *(const float4*)&a_s[m][rg * 4];
      float2 hv = ((const float2*)h2s4)[m * 16 + cg];
      acc[0].x += av.x * hv.x; acc[0].y += av.x * hv.y;
      acc[1].x += av.y * hv.x; acc[1].y += av.y * hv.y;
      acc[2].x += av.z * hv.x; acc[2].y += av.z * hv.y;
      acc[3].x += av.w * hv.x; acc[3].y += av.w * hv.y;
    }
  }
  size_t hpo = (size_t)mq * ((size_t)BB * NN * GC2);
#pragma unroll
  for (int i = 0; i < 4; ++i) {
    *(float2*)(hpart + hpo + ((size_t)(b * NN) + n0 + rg * 4 + i) * GC2 + cg * 2) = acc[i];
  }
}

// ---------------- K5: gated sum over nodes; x = h2lin + sum_q hpart(fp32)[q], node
#define TR 32
__global__ __launch_bounds__(256) void k5(const float* __restrict__ hpart,
                                          const float* __restrict__ h2lin,
                                          const float* __restrict__ node,
                                          const float* __restrict__ Ws,
                                          const float* __restrict__ bs,
                                          const float* __restrict__ Wt,
                                          const float* __restrict__ bt,
                                          float* __restrict__ partials) {
  __shared__ float xs[TR][GC2 + ND];
  __shared__ float red[2][AUXD];
  int t = threadIdx.x;
  int blk = blockIdx.x;
  int b = blk >> 5;
  int n0 = (blk & 31) * TR;
  const size_t QS2 = (size_t)BB * NN * GC2;
  for (int i = t; i < TR * GC2; i += 256) {
    int rr = i >> 5, kk = i & 31;
    size_t idx = ((size_t)(b * NN + n0 + rr)) * GC2 + kk;
    float v = h2lin[idx];
#pragma unroll
    for (int q = 0; q < 4; ++q) v += hpart[q * QS2 + idx];
    xs[rr][kk] = v;
  }
  for (int i = t; i < TR * ND; i += 256) {
    int rr = i >> 5, kk = i & 31;
    xs[rr][GC2 + kk] = node[((size_t)(b * NN + n0 + rr)) * ND + kk];
  }
  int c = t & 127;
  int g = t >> 7;
  float wsc[64], wtc[64];
#pragma unroll
  for (int k = 0; k < 64; ++k) {
    wsc[k] = Ws[(size_t)k * AUXD + c];
    wtc[k] = Wt[(size_t)k * AUXD + c];
  }
  float bsv = bs[c], btv = bt[c];
  __syncthreads();
  float part = 0.f;
  for (int rr = g * (TR / 2); rr < (g + 1) * (TR / 2); ++rr) {
    float as_ = bsv, at_ = btv;
#pragma unroll
    for (int k = 0; k < 64; ++k) {
      float xv = xs[rr][k];
      as_ += xv * wsc[k];
      at_ += xv * wtc[k];
    }
    float sg = 1.f / (1.f + __expf(-as_));
    float e2 = __expf(2.f * at_);
    float th = 1.f - 2.f / (e2 + 1.f);
    part += sg * th;
  }
  red[g][c] = part;
  __syncthreads();
  if (t < AUXD) partials[(size_t)blk * AUXD + t] = red[0][t] + red[1][t];
}

// ---------------- K4_raw fallback (ws too small): h = adj(raw) @ h2 + h2 -> hbuf(fp32)
#define TN2 16
#define TM2 128
__global__ __launch_bounds__(256) void k4_raw(const float* __restrict__ adj_src,
                                              const float* __restrict__ h2lin,
                                              float* __restrict__ hout) {
  __shared__ float a_s[TN2][TM2 + 4];
  __shared__ float h2s[TM2][GC2];
  int t = threadIdx.x;
  int blk = blockIdx.x;
  int b = blk >> 6;
  int n0 = (blk & 63) * TN2;
  const float4* h2b4 = (const float4*)(h2lin + (size_t)b * NN * GC2);
  int r = t >> 4;
  int cg = (t >> 1) & 7;
  int hh = t & 1;
  const size_t rs5 = (size_t)NN * 5;
  float4 acc = make_float4(0.f, 0.f, 0.f, 0.f);

  for (int tile = 0; tile < NN / TM2; ++tile) {
    int m0 = tile * TM2;
    float4 pfr[2][5];
    int x = t & 31, rowp = t >> 5;
#pragma unroll
    for (int p = 0; p < 2; ++p) {
      const float* rp = adj_src + (size_t)(b * NN + n0 + rowp + 8 * p) * rs5 + (size_t)(m0 + 4 * x) * 5;
#pragma unroll
      for (int q = 0; q < 5; ++q) pfr[p][q] = *(const float4*)(rp + 4 * q);
    }
    float4 hf[4];
#pragma unroll
    for (int q = 0; q < 4; ++q) hf[q] = h2b4[m0 * (GC2 / 4) + q * 256 + t];
    __syncthreads();
#pragma unroll
    for (int p = 0; p < 2; ++p) {
      int row = rowp + 8 * p;
      float4 s;
      s.x = pfr[p][0].y + pfr[p][0].z + pfr[p][0].w + pfr[p][1].x;
      s.y = pfr[p][1].z + pfr[p][1].w + pfr[p][2].x + pfr[p][2].y;
      s.z = pfr[p][2].w + pfr[p][3].x + pfr[p][3].y + pfr[p][3].z;
      s.w = pfr[p][4].x + pfr[p][4].y + pfr[p][4].z + pfr[p][4].w;
      *(float4*)&a_s[row][4 * x] = s;
    }
#pragma unroll
    for (int q = 0; q < 4; ++q) ((float4*)h2s)[q * 256 + t] = hf[q];
    __syncthreads();
#pragma unroll 4
    for (int mm = 0; mm < TM2 / 2; mm += 4) {
      int m = hh * (TM2 / 2) + mm;
      float4 av = *(const float4*)&a_s[r][m];
      const float* hp = &h2s[m][cg * 4];
      float4 h0 = *(const float4*)(hp);
      float4 h1v = *(const float4*)(hp + GC2);
      float4 h2v = *(const float4*)(hp + 2 * GC2);
      float4 h3v = *(const float4*)(hp + 3 * GC2);
      acc.x += av.x * h0.x + av.y * h1v.x + av.z * h2v.x + av.w * h3v.x;
      acc.y += av.x * h0.y + av.y * h1v.y + av.z * h2v.y + av.w * h3v.y;
      acc.z += av.x * h0.z + av.y * h1v.z + av.z * h2v.z + av.w * h3v.z;
      acc.w += av.x * h0.w + av.y * h1v.w + av.z * h2v.w + av.w * h3v.w;
    }
    __syncthreads();
  }
  float4* red = (float4*)a_s;
  red[(hh * TN2 + r) * 8 + cg] = acc;
  __syncthreads();
  if (t < 128) {
    int rr = t >> 3, cc = t & 7;
    float4 s0 = red[(0 * TN2 + rr) * 8 + cc];
    float4 s1 = red[(1 * TN2 + rr) * 8 + cc];
    size_t row = (size_t)(b * NN + n0 + rr);
    float4 sv = *(const float4*)(h2lin + row * GC2 + cc * 4);
    float4 o;
    o.x = s0.x + s1.x + sv.x;
    o.y = s0.y + s1.y + sv.y;
    o.z = s0.z + s1.z + sv.z;
    o.w = s0.w + s1.w + sv.w;
    *(float4*)(hout + row * GC2 + cc * 4) = o;
  }
}

// ---------------- K5_fb (fallback path only): gated sum over nodes from fp32 hbuf
__global__ __launch_bounds__(256) void k5_fb(const float* __restrict__ hbuf,
                                             const float* __restrict__ node,
                                             const float* __restrict__ Ws,
                                             const float* __restrict__ bs,
                                             const float* __restrict__ Wt,
                                             const float* __restrict__ bt,
                                             float* __restrict__ partials) {
  __shared__ float xs[TR][GC2 + ND];
  __shared__ float red[2][AUXD];
  int t = threadIdx.x;
  int blk = blockIdx.x;
  int b = blk >> 5;
  int n0 = (blk & 31) * TR;
  for (int i = t; i < TR * GC2; i += 256) {
    int rr = i >> 5, kk = i & 31;
    xs[rr][kk] = hbuf[((size_t)(b * NN + n0 + rr)) * GC2 + kk];
  }
  for (int i = t; i < TR * ND; i += 256) {
    int rr = i >> 5, kk = i & 31;
    xs[rr][GC2 + kk] = node[((size_t)(b * NN + n0 + rr)) * ND + kk];
  }
  int c = t & 127;
  int g = t >> 7;
  float wsc[64], wtc[64];
#pragma unroll
  for (int k = 0; k < 64; ++k) {
    wsc[k] = Ws[(size_t)k * AUXD + c];
    wtc[k] = Wt[(size_t)k * AUXD + c];
  }
  float bsv = bs[c], btv = bt[c];
  __syncthreads();
  float part = 0.f;
  for (int rr = g * (TR / 2); rr < (g + 1) * (TR / 2); ++rr) {
    float as_ = bsv, at_ = btv;
#pragma unroll
    for (int k = 0; k < 64; ++k) {
      float xv = xs[rr][k];
      as_ += xv * wsc[k];
      at_ += xv * wtc[k];
    }
    float sg = 1.f / (1.f + __expf(-as_));
    float e2 = __expf(2.f * at_);
    float th = 1.f - 2.f / (e2 + 1.f);
    part += sg * th;
  }
  red[g][c] = part;
  __syncthreads();
  if (t < AUXD) partials[(size_t)blk * AUXD + t] = red[0][t] + red[1][t];
}

// ---------------- K6: reduce partials, tanh, MLP -> head
__global__ __launch_bounds__(128) void k6(const float* __restrict__ partials,
                                          const float* __restrict__ Wm1, const float* __restrict__ bm1,
                                          const float* __restrict__ Wm2, const float* __restrict__ bm2,
                                          const float* __restrict__ Wl, const float* __restrict__ bl,
                                          float* __restrict__ out) {
  __shared__ float g_s[AUXD];
  __shared__ float g2_s[AUXD];
  int t = threadIdx.x;
  int b = blockIdx.x;
  float s = 0.f;
  for (int j = 0; j < 32; ++j) s += partials[((size_t)(b * 32 + j)) * AUXD + t];
  float e2 = __expf(2.f * s);
  g_s[t] = 1.f - 2.f / (e2 + 1.f);
  __syncthreads();
  float acc = bm1[t];
#pragma unroll 16
  for (int k = 0; k < AUXD; ++k) acc += g_s[k] * Wm1[(size_t)k * 128 + t];
  e2 = __expf(2.f * acc);
  g2_s[t] = 1.f - 2.f / (e2 + 1.f);
  __syncthreads();
  acc = bm2[t];
#pragma unroll 16
  for (int k = 0; k < 128; ++k) acc += g2_s[k] * Wm2[(size_t)k * 128 + t];
  e2 = __expf(2.f * acc);
  float g3 = 1.f - 2.f / (e2 + 1.f);
  __syncthreads();
  g_s[t] = g3;
  __syncthreads();
  if (t < ZD) {
    float a = bl[t];
#pragma unroll 16
    for (int k = 0; k < 128; ++k) a += g_s[k] * Wl[(size_t)k * ZD + t];
    out[(size_t)b * ZD + t] = a;
  }
}

extern "C" void kernel_launch(void* const* d_in, const int* in_sizes, int n_in,
                              void* d_out, int out_size, void* d_ws, size_t ws_size,
                              hipStream_t stream) {
  const float* node = (const float*)d_in[0];
  const float* adj_raw = (const float*)d_in[1];
  const float* W1 = (const float*)d_in[2];
  const float* b1 = (const float*)d_in[3];
  const float* W2 = (const float*)d_in[4];
  const float* b2 = (const float*)d_in[5];
  const float* Ws = (const float*)d_in[6];
  const float* bs = (const float*)d_in[7];
  const float* Wt = (const float*)d_in[8];
  const float* bt = (const float*)d_in[9];
  const float* Wm1 = (const float*)d_in[10];
  const float* bm1 = (const float*)d_in[11];
  const float* Wm2 = (const float*)d_in[12];
  const float* bm2 = (const float*)d_in[13];
  const float* Wl = (const float*)d_in[14];
  const float* bl = (const float*)d_in[15];
  float* out = (float*)d_out;
  float* ws = (float*)d_ws;

  size_t o_h1 = 0;                                       // floats
  size_t o_msgp = o_h1 + (size_t)BB * NN * GC1;          // msg fp16: 4 slices = 2M floats
  size_t o_h2 = o_msgp + 2 * (size_t)BB * NN * GC1;
  size_t o_hp = o_h2 + (size_t)BB * NN * GC2;            // hpart fp32: 4 slices (fallback hbuf = slice 0)
  size_t o_part = o_hp + 4 * (size_t)BB * NN * GC2;
  size_t o_adj = o_part + (size_t)512 * AUXD;            // adj_s fp16
  size_t need_bytes = o_adj * sizeof(float) + (size_t)BB * NN * NN * sizeof(__half);
  bool store = (ws_size >= need_bytes);

  float* h1lin = ws + o_h1;
  __half* msgh = (__half*)(ws + o_msgp);
  float* h2lin = ws + o_h2;
  float* hpart = ws + o_hp;
  float* part = ws + o_part;
  __half* adj_sh = (__half*)(ws + o_adj);

  k1<<<4096, 256, 0, stream>>>(node, W1, b1, h1lin);
  k2<<<1024, 256, 0, stream>>>(adj_raw, h1lin, adj_sh, msgh, store ? 1 : 0);
  k3<<<2048, 256, 0, stream>>>(msgh, h1lin, W2, b2, h2lin);
  if (store) {
    k4<<<1024, 256, 0, stream>>>(adj_sh, h2lin, hpart);
    k5<<<512, 256, 0, stream>>>(hpart, h2lin, node, Ws, bs, Wt, bt, part);
  } else {
    k4_raw<<<1024, 256, 0, stream>>>(adj_raw, h2lin, hpart);
    k5_fb<<<512, 256, 0, stream>>>(hpart, node, Ws, bs, Wt, bt, part);
  }
  k6<<<16, 128, 0, stream>>>(part, Wm1, bm1, Wm2, bm2, Wl, bl, out);
}